// Round 6
// baseline (3690.267 us; speedup 1.0000x reference)
//
#include <hip/hip_runtime.h>
#include <math.h>

#define AGENTS 128
#define DIM 256
#define NHEADS 8
#define MEM_LEN 1024
#define PRED 12
#define MAXS (PRED * AGENTS)   // 1536
#define NWG 16

typedef __attribute__((ext_vector_type(8))) short short8;
typedef __attribute__((ext_vector_type(4))) float f32x4;

#define MFMA(a, b, c) __builtin_amdgcn_mfma_f32_16x16x32_bf16(a, b, c, 0, 0, 0)

__device__ __forceinline__ unsigned short f2bf(float f) {
  union { float f; unsigned u; } v; v.f = f;
  unsigned r = v.u + 0x7fffu + ((v.u >> 16) & 1u);   // RNE
  return (unsigned short)(r >> 16);
}

__device__ __forceinline__ short8 afrag8(const float* p) {
  float4 a = *(const float4*)p;
  float4 b = *(const float4*)(p + 4);
  short8 r;
  r[0] = (short)f2bf(a.x); r[1] = (short)f2bf(a.y);
  r[2] = (short)f2bf(a.z); r[3] = (short)f2bf(a.w);
  r[4] = (short)f2bf(b.x); r[5] = (short)f2bf(b.y);
  r[6] = (short)f2bf(b.z); r[7] = (short)f2bf(b.w);
  return r;
}

__device__ __forceinline__ void ln_stats(const float* __restrict__ pst, int row,
                                         float& mean, float& rstd) {
  float4 p0 = *(const float4*)(pst + row * 8);
  float4 p1 = *(const float4*)(pst + row * 8 + 4);
  float s  = p0.x + p0.z + p1.x + p1.z;
  float ss = p0.y + p0.w + p1.y + p1.w;
  mean = s * (1.0f / 256.0f);
  rstd = rsqrtf(ss * (1.0f / 256.0f) - mean * mean + 1e-5f);
}

__device__ __forceinline__ short8 afragLN(const float* __restrict__ yr,
                                          const float* __restrict__ lg,
                                          const float* __restrict__ lb,
                                          int k, float mean, float rstd) {
  float4 a = *(const float4*)(yr + k), b = *(const float4*)(yr + k + 4);
  float4 ga = *(const float4*)(lg + k), gb = *(const float4*)(lg + k + 4);
  float4 ba = *(const float4*)(lb + k), bb = *(const float4*)(lb + k + 4);
  short8 r;
  r[0] = (short)f2bf((a.x - mean) * rstd * ga.x + ba.x);
  r[1] = (short)f2bf((a.y - mean) * rstd * ga.y + ba.y);
  r[2] = (short)f2bf((a.z - mean) * rstd * ga.z + ba.z);
  r[3] = (short)f2bf((a.w - mean) * rstd * ga.w + ba.w);
  r[4] = (short)f2bf((b.x - mean) * rstd * gb.x + bb.x);
  r[5] = (short)f2bf((b.y - mean) * rstd * gb.y + bb.y);
  r[6] = (short)f2bf((b.z - mean) * rstd * gb.z + bb.z);
  r[7] = (short)f2bf((b.w - mean) * rstd * gb.w + bb.w);
  return r;
}

// ---------------------------------------------------------------------------
struct MegaP {
  const float *ds, *mask;
  const float *in_b, *out_W, *out_b;
  const float *sa_bq, *sa_bk, *sa_bv, *sa_bo;
  const float *ca_bq, *ca_bo;
  const float *ff_b1, *ff_b2;
  const float *ln1_g, *ln1_b, *ln2_g, *ln2_b, *ln3_g, *ln3_b;
  float *out;
  float *sceneArr;                   // [13][256]
  float *x0, *Y1, *Y2, *Y3;
  float *pst1, *pst2, *pst3;
  const float *peA, *peT;
  unsigned short *xb0, *abuf, *mid;
  unsigned short *saK, *saV, *memK, *memV;
  const unsigned short *dxdb, *ffW1b, *ffW2b, *inWb;
  unsigned *barCnt, *barGen;
};

// sense-reversing device-scope grid barrier
__device__ __forceinline__ void gridbar(unsigned* cnt, unsigned* gen) {
  __syncthreads();
  if (threadIdx.x == 0) {
    __threadfence();
    unsigned g = __hip_atomic_load(gen, __ATOMIC_RELAXED, __HIP_MEMORY_SCOPE_AGENT);
    unsigned a = __hip_atomic_fetch_add(cnt, 1u, __ATOMIC_ACQ_REL, __HIP_MEMORY_SCOPE_AGENT);
    if (a == (unsigned)(NWG - 1)) {
      __hip_atomic_store(cnt, 0u, __ATOMIC_RELAXED, __HIP_MEMORY_SCOPE_AGENT);
      __hip_atomic_store(gen, g + 1u, __ATOMIC_RELEASE, __HIP_MEMORY_SCOPE_AGENT);
    } else {
      while (__hip_atomic_load(gen, __ATOMIC_ACQUIRE, __HIP_MEMORY_SCOPE_AGENT) == g)
        __builtin_amdgcn_s_sleep(1);
    }
    __threadfence();
  }
  __syncthreads();
}

// ---------------------------------------------------------------------------
// embed phase (8 WGs): [prev-step out-proj + scene update] + embed GEMM
// ---------------------------------------------------------------------------
__device__ void embed_phase(const MegaP& p, int wg, int s) {
  if (wg >= 8) return;
  __shared__ float sscene[256];
  const int tid = threadIdx.x;
  if (s > 0) {
    const int row = tid >> 1, j = tid & 1;
    float mean, rstd; ln_stats(p.pst3, row, mean, rstd);
    const float* yr = p.Y3 + row * 256;
    const float* wr = p.out_W + j * 256;
    const float* g3 = p.ln3_g + 256;
    const float* b3 = p.ln3_b + 256;
    float a = 0.f;
    for (int k = 0; k < 256; k += 4) {
      float4 y = *(const float4*)(yr + k);
      float4 gg = *(const float4*)(g3 + k);
      float4 bb = *(const float4*)(b3 + k);
      float4 ww = *(const float4*)(wr + k);
      a += ((y.x - mean) * rstd * gg.x + bb.x) * ww.x
         + ((y.y - mean) * rstd * gg.y + bb.y) * ww.y
         + ((y.z - mean) * rstd * gg.z + bb.z) * ww.z
         + ((y.w - mean) * rstd * gg.w + bb.w) * ww.w;
    }
    a += p.out_b[j];
    float sv = p.sceneArr[(s - 1) * 256 + row * 2 + j] + a;
    if (wg == 0) p.out[((s - 1) * AGENTS + row) * 2 + j] = a;
    p.sceneArr[s * 256 + row * 2 + j] = sv;   // identical dup-writes: benign
    sscene[row * 2 + j] = sv;
  } else {
    sscene[tid] = p.sceneArr[tid];
  }
  __syncthreads();

  const int l = tid & 63, w = tid >> 6;
  const int c15 = l & 15, g8 = (l >> 4) * 8, r0v = (l >> 4) * 4;
  const int rowb = (wg >> 2) * 64 + w * 16;
  const int arow = rowb + c15;
  const int colb = (wg & 3) * 64;
  f32x4 acc[4] = {};
  const unsigned short* wp = p.inWb + (colb + c15) * 160 + g8;
  for (int kc = 0; kc < 5; ++kc) {
    short8 af;
#pragma unroll
    for (int j = 0; j < 8; ++j) {
      int kk = kc * 32 + g8 + j;
      float v = (kk < 2) ? sscene[arow * 2 + kk]
                         : ((kk < 130) ? p.ds[arow * 128 + (kk - 2)] : 0.f);
      af[j] = (short)f2bf(v);
    }
#pragma unroll
    for (int t = 0; t < 4; ++t)
      acc[t] = MFMA(af, *(const short8*)(wp + t * 16 * 160 + kc * 32), acc[t]);
  }
#pragma unroll
  for (int t = 0; t < 4; ++t) {
    const int col = colb + t * 16 + c15;
    const float bb = p.in_b[col] + p.peT[s * DIM + col];
#pragma unroll
    for (int r = 0; r < 4; ++r) {
      const int row = rowb + r0v + r;
      float v = acc[t][r] + bb + p.peA[row * DIM + col];
      p.x0[row * DIM + col] = v;
      p.xb0[row * DIM + col] = f2bf(v);
    }
  }
}

// ---------------------------------------------------------------------------
// K/V projection into caches (16 WGs). AMODE: 0 bf16 ab; 1 fp32 Y + LN.
// ---------------------------------------------------------------------------
template <int AMODE>
__device__ void kv_phase(const MegaP& p, int wg,
    const unsigned short* __restrict__ ab,
    const float* __restrict__ Ya, const float* __restrict__ psta,
    const float* __restrict__ lga, const float* __restrict__ lba,
    const unsigned short* __restrict__ Wk, const float* __restrict__ bk,
    const unsigned short* __restrict__ Wv, const float* __restrict__ bv,
    unsigned short* __restrict__ Ko, unsigned short* __restrict__ Vo,
    int Spad, int crow)
{
  const int tid = threadIdx.x, l = tid & 63, w = tid >> 6;
  const int c15 = l & 15, g8 = (l >> 4) * 8, r0v = (l >> 4) * 4;
  const int rowb = (wg >> 3) * 64 + w * 16;
  const int arow = rowb + c15;
  const int y = wg & 7;
  const bool isK = y < 4;
  const int colb = (y & 3) * 64;
  const unsigned short* W = isK ? Wk : Wv;
  const float* bias = isK ? bk : bv;

  float meanA = 0.f, rstdA = 0.f;
  if (AMODE == 1) ln_stats(psta, arow, meanA, rstdA);

  f32x4 acc[4] = {};
  const unsigned short* wp = W + (colb + c15) * 256 + g8;
  for (int kc = 0; kc < 8; ++kc) {
    short8 af;
    if (AMODE == 0) af = *(const short8*)(ab + arow * 256 + kc * 32 + g8);
    else af = afragLN(Ya + arow * 256, lga, lba, kc * 32 + g8, meanA, rstdA);
#pragma unroll
    for (int t = 0; t < 4; ++t)
      acc[t] = MFMA(af, *(const short8*)(wp + t * 16 * 256 + kc * 32), acc[t]);
  }
#pragma unroll
  for (int t = 0; t < 4; ++t) {
    const int col = colb + t * 16 + c15;
    const float bb = bias[col];
    const int hh = col >> 5, d = col & 31;
#pragma unroll
    for (int r = 0; r < 4; ++r) {
      const int row = crow + rowb + r0v + r;
      unsigned short val = f2bf(acc[t][r] + bb);
      if (isK) Ko[hh * Spad * 32 + row * 32 + d] = val;
      else     Vo[col * Spad + row] = val;
    }
  }
}

// ---------------------------------------------------------------------------
// Attention + fused Q-projection (16 WGs = 2 row-blocks x 8 heads).
// ---------------------------------------------------------------------------
template <int AMODE>
__device__ void attn_phase(const MegaP& p, int wg,
    const unsigned short* __restrict__ ab,
    const float* __restrict__ Ya, const float* __restrict__ psta,
    const float* __restrict__ lga, const float* __restrict__ lba,
    const unsigned short* __restrict__ Wq, const float* __restrict__ bq,
    const unsigned short* __restrict__ Kc, const unsigned short* __restrict__ Vt,
    unsigned short* __restrict__ Ob, int S, int Spad)
{
  __shared__ unsigned short sq[4][16][32];
  __shared__ unsigned short ps[4][16][96];
  const int tid = threadIdx.x, l = tid & 63, w = tid >> 6;
  const int c15 = l & 15, g = l >> 4, g8 = g * 8, r0v = g * 4;
  const int h = wg & 7;
  const int rowb = (wg >> 3) * 64 + w * 16;
  const int arow = rowb + c15;

  float meanA = 0.f, rstdA = 0.f;
  if (AMODE == 1) ln_stats(psta, arow, meanA, rstdA);
  f32x4 q0 = {}, q1 = {};
  const unsigned short* wp = Wq + (h * 32 + c15) * 256 + g8;
  for (int kc = 0; kc < 8; ++kc) {
    short8 af;
    if (AMODE == 0) af = *(const short8*)(ab + arow * 256 + kc * 32 + g8);
    else af = afragLN(Ya + arow * 256, lga, lba, kc * 32 + g8, meanA, rstdA);
    q0 = MFMA(af, *(const short8*)(wp + kc * 32), q0);
    q1 = MFMA(af, *(const short8*)(wp + 16 * 256 + kc * 32), q1);
  }
  {
    const float b0 = bq[h * 32 + c15], b1 = bq[h * 32 + 16 + c15];
#pragma unroll
    for (int r = 0; r < 4; ++r) {
      sq[w][r0v + r][c15]      = f2bf(q0[r] + b0);
      sq[w][r0v + r][16 + c15] = f2bf(q1[r] + b1);
    }
  }
  short8 qf = *(const short8*)&sq[w][c15][g8];   // wave-private

  float mk[2][4][4];
#pragma unroll
  for (int pp = 0; pp < 2; ++pp)
#pragma unroll
    for (int t = 0; t < 4; ++t)
#pragma unroll
      for (int r = 0; r < 4; ++r)
        mk[pp][t][r] = p.mask[arow * AGENTS + pp * 64 + t * 16 + g * 4 + r];

  const unsigned short* kh = Kc + h * Spad * 32;
  const unsigned short* vh = Vt + h * 32 * Spad;
  unsigned short* pq = &ps[w][0][0];
  const float scale = 0.17677669529663687f;
  f32x4 oa0 = {}, oa1 = {};
  float lsum = 0.f;

  for (int kc = 0; kc < S; kc += 64) {
    const int pp = (kc >> 6) & 1;
#pragma unroll
    for (int t = 0; t < 4; ++t) {
      short8 kf = *(const short8*)(kh + (kc + t * 16 + c15) * 32 + g8);
      f32x4 zz = {};
      f32x4 sc = MFMA(kf, qf, zz);
      float e0 = __expf(sc[0] * scale + mk[pp][t][0]);
      float e1 = __expf(sc[1] * scale + mk[pp][t][1]);
      float e2 = __expf(sc[2] * scale + mk[pp][t][2]);
      float e3 = __expf(sc[3] * scale + mk[pp][t][3]);
      unsigned short b0 = f2bf(e0), b1 = f2bf(e1), b2 = f2bf(e2), b3 = f2bf(e3);
      union { unsigned u; float f; } c0, c1, c2, c3;
      c0.u = (unsigned)b0 << 16; c1.u = (unsigned)b1 << 16;
      c2.u = (unsigned)b2 << 16; c3.u = (unsigned)b3 << 16;
      lsum += c0.f + c1.f + c2.f + c3.f;
      uint2 u2;
      u2.x = (unsigned)b0 | ((unsigned)b1 << 16);
      u2.y = (unsigned)b2 | ((unsigned)b3 << 16);
      *(uint2*)&pq[c15 * 96 + t * 16 + g * 4] = u2;
    }
#pragma unroll
    for (int ks = 0; ks < 2; ++ks) {
      short8 pf = *(const short8*)&pq[c15 * 96 + ks * 32 + g8];
      short8 v0 = *(const short8*)(vh + c15 * Spad + kc + ks * 32 + g8);
      short8 v1 = *(const short8*)(vh + (16 + c15) * Spad + kc + ks * 32 + g8);
      oa0 = MFMA(v0, pf, oa0);
      oa1 = MFMA(v1, pf, oa1);
    }
  }
  lsum += __shfl_xor(lsum, 16, 64);
  lsum += __shfl_xor(lsum, 32, 64);
  const float inv = 1.0f / lsum;
#pragma unroll
  for (int r = 0; r < 4; ++r) {
    Ob[arow * DIM + h * 32 + g * 4 + r]      = f2bf(oa0[r] * inv);
    Ob[arow * DIM + h * 32 + 16 + g * 4 + r] = f2bf(oa1[r] * inv);
  }
}

// ---------------------------------------------------------------------------
// 64x64 projection + residual + partial LN stats (8 WGs).
// AMODE: 0 bf16 A; RES: 1 plain fp32 resid; 2 LN resid.
// ---------------------------------------------------------------------------
template <int RES>
__device__ void wproj_phase(const MegaP& p, int wg,
    const unsigned short* __restrict__ ab, int lda,
    const unsigned short* __restrict__ W, const float* __restrict__ bias, int K,
    const float* __restrict__ res,
    const float* __restrict__ Yp, const float* __restrict__ pstp,
    const float* __restrict__ gp, const float* __restrict__ bp,
    float* __restrict__ Yo, float* __restrict__ psto)
{
  if (wg >= 8) return;
  const int tid = threadIdx.x, l = tid & 63, w = tid >> 6;
  const int c15 = l & 15, g8 = (l >> 4) * 8, r0v = (l >> 4) * 4;
  const int rowb = (wg >> 2) * 64 + w * 16;
  const int arow = rowb + c15;
  const int cb = wg & 3;
  const int colb = cb * 64;

  const int KC = K >> 5;
  f32x4 acc[4] = {};
  const unsigned short* wp = W + (colb + c15) * K + g8;
  for (int kc = 0; kc < KC; ++kc) {
    short8 af = *(const short8*)(ab + arow * lda + kc * 32 + g8);
#pragma unroll
    for (int t = 0; t < 4; ++t)
      acc[t] = MFMA(af, *(const short8*)(wp + t * 16 * K + kc * 32), acc[t]);
  }

  float mp[4], rp[4];
  if (RES == 2) {
#pragma unroll
    for (int r = 0; r < 4; ++r) ln_stats(pstp, rowb + r0v + r, mp[r], rp[r]);
  }
  float v[4][4];
#pragma unroll
  for (int t = 0; t < 4; ++t) {
    const int col = colb + t * 16 + c15;
    const float bb = bias[col];
    float gpp = 0.f, bpp = 0.f;
    if (RES == 2) { gpp = gp[col]; bpp = bp[col]; }
#pragma unroll
    for (int r = 0; r < 4; ++r) {
      const int row = rowb + r0v + r;
      float x = acc[t][r] + bb;
      if (RES == 1) x += res[row * 256 + col];
      if (RES == 2) x += (Yp[row * 256 + col] - mp[r]) * rp[r] * gpp + bpp;
      Yo[row * 256 + col] = x;
      v[t][r] = x;
    }
  }
#pragma unroll
  for (int r = 0; r < 4; ++r) {
    float s  = v[0][r] + v[1][r] + v[2][r] + v[3][r];
    float ss = v[0][r]*v[0][r] + v[1][r]*v[1][r] + v[2][r]*v[2][r] + v[3][r]*v[3][r];
#pragma unroll
    for (int m = 1; m < 16; m <<= 1) {
      s  += __shfl_xor(s, m, 64);
      ss += __shfl_xor(ss, m, 64);
    }
    if (c15 == 0) {
      const int row = rowb + r0v + r;
      psto[row * 8 + cb * 2]     = s;
      psto[row * 8 + cb * 2 + 1] = ss;
    }
  }
}

// ---------------------------------------------------------------------------
// FF1 (16 WGs = 2 row-blocks x 8 col-blocks of 128): LN(Y2) @ W1 + relu -> mid
// ---------------------------------------------------------------------------
__device__ void ff1_phase(const MegaP& p, int wg,
    const float* __restrict__ Ya, const float* __restrict__ psta,
    const float* __restrict__ lga, const float* __restrict__ lba,
    const unsigned short* __restrict__ W1, const float* __restrict__ b1)
{
  const int tid = threadIdx.x, l = tid & 63, w = tid >> 6;
  const int c15 = l & 15, g8 = (l >> 4) * 8, r0v = (l >> 4) * 4;
  const int rowb = (wg >> 3) * 64 + w * 16;
  const int arow = rowb + c15;
  const int colb = (wg & 7) * 128;
  float mean, rstd; ln_stats(psta, arow, mean, rstd);
  f32x4 acc[8] = {};
  const unsigned short* wp = W1 + (colb + c15) * 256 + g8;
  for (int kc = 0; kc < 8; ++kc) {
    short8 af = afragLN(Ya + arow * 256, lga, lba, kc * 32 + g8, mean, rstd);
#pragma unroll
    for (int t = 0; t < 8; ++t)
      acc[t] = MFMA(af, *(const short8*)(wp + t * 16 * 256 + kc * 32), acc[t]);
  }
#pragma unroll
  for (int t = 0; t < 8; ++t) {
    const int col = colb + t * 16 + c15;
    const float bb = b1[col];
#pragma unroll
    for (int r = 0; r < 4; ++r)
      p.mid[(rowb + r0v + r) * 1024 + col] = f2bf(fmaxf(acc[t][r] + bb, 0.f));
  }
}

// final out-projection for the last step (1 WG)
__device__ void final_phase(const MegaP& p, int wg) {
  if (wg != 0) return;
  const int tid = threadIdx.x;
  const int row = tid >> 1, j = tid & 1;
  float mean, rstd; ln_stats(p.pst3, row, mean, rstd);
  const float* yr = p.Y3 + row * 256;
  const float* wr = p.out_W + j * 256;
  const float* g3 = p.ln3_g + 256;
  const float* b3 = p.ln3_b + 256;
  float a = 0.f;
  for (int k = 0; k < 256; k += 4) {
    float4 y = *(const float4*)(yr + k);
    float4 gg = *(const float4*)(g3 + k);
    float4 bb = *(const float4*)(b3 + k);
    float4 ww = *(const float4*)(wr + k);
    a += ((y.x - mean) * rstd * gg.x + bb.x) * ww.x
       + ((y.y - mean) * rstd * gg.y + bb.y) * ww.y
       + ((y.z - mean) * rstd * gg.z + bb.z) * ww.z
       + ((y.w - mean) * rstd * gg.w + bb.w) * ww.w;
  }
  a += p.out_b[j];
  p.out[((PRED - 1) * AGENTS + row) * 2 + j] = a;
}

// ---------------------------------------------------------------------------
// THE mega kernel: all 12 AR steps, grid-barrier between phases.
// ---------------------------------------------------------------------------
__global__ __launch_bounds__(256, 1) void mega_k(MegaP p) {
  const int wg = blockIdx.x;
#define GB gridbar(p.barCnt, p.barGen)
  for (int s = 0; s < PRED; ++s) {
    embed_phase(p, wg, s);
    GB;
    for (int l = 0; l < 2; ++l) {
      const unsigned short* saWq = p.dxdb + 0 * 131072 + l * 65536;
      const unsigned short* saWk = p.dxdb + 1 * 131072 + l * 65536;
      const unsigned short* saWv = p.dxdb + 2 * 131072 + l * 65536;
      const unsigned short* saWo = p.dxdb + 3 * 131072 + l * 65536;
      const unsigned short* caWq = p.dxdb + 4 * 131072 + l * 65536;
      const unsigned short* caWo = p.dxdb + 7 * 131072 + l * 65536;
      unsigned short* saKl = p.saK + l * MAXS * 256;
      unsigned short* saVl = p.saV + l * MAXS * 256;
      unsigned short* memKl = p.memK + l * 262144;
      unsigned short* memVl = p.memV + l * 262144;

      if (l == 0) {
        kv_phase<0>(p, wg, p.xb0, nullptr, nullptr, nullptr, nullptr,
                    saWk, p.sa_bk, saWv, p.sa_bv, saKl, saVl, MAXS, s * AGENTS);
        GB;
        attn_phase<0>(p, wg, p.xb0, nullptr, nullptr, nullptr, nullptr,
                      saWq, p.sa_bq, saKl, saVl, p.abuf, (s + 1) * AGENTS, MAXS);
        GB;
        wproj_phase<1>(p, wg, p.abuf, 256, saWo, p.sa_bo, 256,
                       p.x0, nullptr, nullptr, nullptr, nullptr, p.Y1, p.pst1);
        GB;
      } else {
        kv_phase<1>(p, wg, nullptr, p.Y3, p.pst3, p.ln3_g, p.ln3_b,
                    saWk, p.sa_bk + 256, saWv, p.sa_bv + 256, saKl, saVl,
                    MAXS, s * AGENTS);
        GB;
        attn_phase<1>(p, wg, nullptr, p.Y3, p.pst3, p.ln3_g, p.ln3_b,
                      saWq, p.sa_bq + 256, saKl, saVl, p.abuf, (s + 1) * AGENTS, MAXS);
        GB;
        wproj_phase<2>(p, wg, p.abuf, 256, saWo, p.sa_bo + 256, 256,
                       nullptr, p.Y3, p.pst3, p.ln3_g, p.ln3_b, p.Y1, p.pst1);
        GB;
      }
      attn_phase<1>(p, wg, nullptr, p.Y1, p.pst1, p.ln1_g + l * 256, p.ln1_b + l * 256,
                    caWq, p.ca_bq + l * 256, memKl, memVl, p.abuf, MEM_LEN, MEM_LEN);
      GB;
      wproj_phase<2>(p, wg, p.abuf, 256, caWo, p.ca_bo + l * 256, 256,
                     nullptr, p.Y1, p.pst1, p.ln1_g + l * 256, p.ln1_b + l * 256,
                     p.Y2, p.pst2);
      GB;
      ff1_phase(p, wg, p.Y2, p.pst2, p.ln2_g + l * 256, p.ln2_b + l * 256,
                p.ffW1b + l * 262144, p.ff_b1 + l * 1024);
      GB;
      wproj_phase<2>(p, wg, p.mid, 1024, p.ffW2b + l * 262144, p.ff_b2 + l * 256, 1024,
                     nullptr, p.Y2, p.pst2, p.ln2_g + l * 256, p.ln2_b + l * 256,
                     p.Y3, p.pst3);
      GB;
    }
  }
  final_phase(p, wg);
#undef GB
}

// ---------------------------------------------------------------------------
// Prologue kernels
// ---------------------------------------------------------------------------
__global__ void cvt8_k(const float* p0, const float* p1, const float* p2,
                       const float* p3, const float* p4, const float* p5,
                       const float* p6, const float* p7, unsigned short* dst)
{
  const float* s;
  switch (blockIdx.z) {
    case 0: s = p0; break; case 1: s = p1; break;
    case 2: s = p2; break; case 3: s = p3; break;
    case 4: s = p4; break; case 5: s = p5; break;
    case 6: s = p6; break; default: s = p7; break;
  }
  int i = blockIdx.x * 256 + threadIdx.x;
  dst[blockIdx.z * 131072 + i] = f2bf(s[i]);
}

__global__ void cvtff_k(const float* w1, const float* w2, unsigned short* dst)
{
  const float* s = blockIdx.z ? w2 : w1;
  int i = blockIdx.x * 256 + threadIdx.x;
  dst[blockIdx.z * 524288 + i] = f2bf(s[i]);
}

__global__ void cvtinw_k(const float* w, unsigned short* dst)
{
  int i = blockIdx.x * 256 + threadIdx.x;
  if (i >= 256 * 160) return;
  int n = i / 160, k = i - n * 160;
  dst[i] = (k < 130) ? f2bf(w[n * 130 + k]) : (unsigned short)0;
}

__global__ void pe_k(float* peA, float* peT)
{
  int i = blockIdx.x * 256 + threadIdx.x;
  if (i < 128 * 256) {
    int row = i >> 8, c = i & 255, pp = c >> 1;
    float dv = expf((float)(2 * pp) * (-9.210340371976184f / 256.f));
    float ang = (float)row * dv;
    peA[i] = (c & 1) ? cosf(ang) : sinf(ang);
  } else if (i < 140 * 256) {
    int j = i - 32768;
    int s = j >> 8, c = j & 255, pp = c >> 1;
    float dv = expf((float)(2 * pp) * (-9.210340371976184f / 256.f));
    float ang = (float)s * dv;
    peT[j] = (c & 1) ? cosf(ang) : sinf(ang);
  }
}

// memory K/V precompute: grid (16, 8, 2) — z = layer
__global__ __launch_bounds__(256) void memkv_k(
    const float* __restrict__ mem, const unsigned short* __restrict__ dxd,
    const float* __restrict__ bk, const float* __restrict__ bvv,
    unsigned short* __restrict__ memK, unsigned short* __restrict__ memV)
{
  const int li = blockIdx.z;
  const int y = blockIdx.y;
  const bool isK = y < 4;
  const int colb = (y & 3) * 64;
  const unsigned short* W = dxd + (isK ? 5 : 6) * 131072 + li * 65536;
  const float* bias = (isK ? bk : bvv) + li * 256;
  unsigned short* Ko = memK + li * MEM_LEN * 256;
  unsigned short* Vo = memV + li * MEM_LEN * 256;
  const int tid = threadIdx.x, l = tid & 63, w = tid >> 6;
  const int c15 = l & 15, g8 = (l >> 4) * 8, r0v = (l >> 4) * 4;
  const int rowb = blockIdx.x * 64 + w * 16;
  const int arow = rowb + c15;
  f32x4 acc[4] = {};
  const unsigned short* wp = W + (colb + c15) * 256 + g8;
  for (int kc = 0; kc < 8; ++kc) {
    short8 af = afrag8(mem + arow * 256 + kc * 32 + g8);
#pragma unroll
    for (int t = 0; t < 4; ++t)
      acc[t] = MFMA(af, *(const short8*)(wp + t * 16 * 256 + kc * 32), acc[t]);
  }
#pragma unroll
  for (int t = 0; t < 4; ++t) {
    const int col = colb + t * 16 + c15;
    const float bb = bias[col];
    const int hh = col >> 5, d = col & 31;
#pragma unroll
    for (int r = 0; r < 4; ++r) {
      const int row = rowb + r0v + r;
      unsigned short val = f2bf(acc[t][r] + bb);
      if (isK) Ko[hh * MEM_LEN * 32 + row * 32 + d] = val;
      else     Vo[col * MEM_LEN + row] = val;
    }
  }
}

__global__ void initbar_k(unsigned* b) { b[0] = 0; b[1] = 0; }

// ---------------------------------------------------------------------------
extern "C" void kernel_launch(void* const* d_in, const int* in_sizes, int n_in,
                              void* d_out, int out_size, void* d_ws, size_t ws_size,
                              hipStream_t stream)
{
  const float* last_pos      = (const float*)d_in[0];
  const float* decoder_state = (const float*)d_in[1];
  const float* memory        = (const float*)d_in[2];
  const float* agent_mask    = (const float*)d_in[3];
  const float* in_W  = (const float*)d_in[4];
  const float* in_b  = (const float*)d_in[5];
  const float* out_W = (const float*)d_in[6];
  const float* out_b = (const float*)d_in[7];

  // fp32 workspace
  float* ws    = (float*)d_ws;
  float* sceneArr = ws;                 // 13*256
  float* x0    = sceneArr + 13 * 256;
  float* Y1    = x0 + 32768;
  float* Y2    = Y1 + 32768;
  float* Y3    = Y2 + 32768;
  float* pst1  = Y3 + 32768;
  float* pst2  = pst1 + 1024;
  float* pst3  = pst2 + 1024;
  float* peA   = pst3 + 1024;
  float* peT   = peA + 32768;
  unsigned short* xb0   = (unsigned short*)(peT + 3072);
  unsigned short* abuf  = xb0 + 32768;
  unsigned short* mid   = abuf + 32768;
  unsigned short* saK   = mid + 131072;
  unsigned short* saV   = saK + 2 * MAXS * 256;
  unsigned short* memK  = saV + 2 * MAXS * 256;
  unsigned short* memV  = memK + 2 * MEM_LEN * 256;
  unsigned short* dxdb  = memV + 2 * MEM_LEN * 256;
  unsigned short* ffW1b = dxdb + 8 * 131072;
  unsigned short* ffW2b = ffW1b + 524288;
  unsigned short* inWb  = ffW2b + 524288;
  unsigned* bar = (unsigned*)(inWb + 40960);

  const dim3 blk(256);

  // prologue
  cvt8_k<<<dim3(512, 1, 8), blk, 0, stream>>>(
      (const float*)d_in[8], (const float*)d_in[10], (const float*)d_in[12],
      (const float*)d_in[14], (const float*)d_in[16], (const float*)d_in[18],
      (const float*)d_in[20], (const float*)d_in[22], dxdb);
  cvtff_k<<<dim3(2048, 1, 2), blk, 0, stream>>>((const float*)d_in[24],
                                                (const float*)d_in[26], ffW1b);
  cvtinw_k<<<160, blk, 0, stream>>>(in_W, inWb);
  pe_k<<<140, blk, 0, stream>>>(peA, peT);
  memkv_k<<<dim3(16, 8, 2), blk, 0, stream>>>(memory, dxdb,
      (const float*)d_in[19], (const float*)d_in[21], memK, memV);
  initbar_k<<<1, 1, 0, stream>>>(bar);
  hipMemcpyAsync(sceneArr, last_pos, 256 * sizeof(float),
                 hipMemcpyDeviceToDevice, stream);

  MegaP p;
  p.ds = decoder_state; p.mask = agent_mask;
  p.in_b = in_b; p.out_W = out_W; p.out_b = out_b;
  p.sa_bq = (const float*)d_in[9];  p.sa_bk = (const float*)d_in[11];
  p.sa_bv = (const float*)d_in[13]; p.sa_bo = (const float*)d_in[15];
  p.ca_bq = (const float*)d_in[17]; p.ca_bo = (const float*)d_in[23];
  p.ff_b1 = (const float*)d_in[25]; p.ff_b2 = (const float*)d_in[27];
  p.ln1_g = (const float*)d_in[28]; p.ln1_b = (const float*)d_in[29];
  p.ln2_g = (const float*)d_in[30]; p.ln2_b = (const float*)d_in[31];
  p.ln3_g = (const float*)d_in[32]; p.ln3_b = (const float*)d_in[33];
  p.out = (float*)d_out;
  p.sceneArr = sceneArr; p.x0 = x0; p.Y1 = Y1; p.Y2 = Y2; p.Y3 = Y3;
  p.pst1 = pst1; p.pst2 = pst2; p.pst3 = pst3;
  p.peA = peA; p.peT = peT;
  p.xb0 = xb0; p.abuf = abuf; p.mid = mid;
  p.saK = saK; p.saV = saV; p.memK = memK; p.memV = memV;
  p.dxdb = dxdb; p.ffW1b = ffW1b; p.ffW2b = ffW2b; p.inWb = inWb;
  p.barCnt = bar; p.barGen = bar + 1;

  mega_k<<<dim3(NWG), blk, 0, stream>>>(p);
}